// Round 11
// baseline (22026.430 us; speedup 1.0000x reference)
//
#include <hip/hip_runtime.h>
#include <math.h>

typedef float f32x2 __attribute__((ext_vector_type(2)));
typedef float f32x4 __attribute__((ext_vector_type(4)));

#define LOG2E 1.4426950408889634f

__device__ __forceinline__ float rcp_fast(float x)  { return __builtin_amdgcn_rcpf(x); }
__device__ __forceinline__ float exp2_fast(float x) { return __builtin_amdgcn_exp2f(x); }
__device__ __forceinline__ float exp_fast(float x)  { return exp2_fast(x * LOG2E); }

// tanh(x) = 1 - 2/(e^{2x}+1). Saturates correctly at +-1.
__device__ __forceinline__ float tanh_fast(float x) {
    float e = exp2_fast(x * (2.0f * LOG2E));
    return 1.0f - 2.0f * rcp_fast(e + 1.0f);
}
// 0.5*(tanh(5x)+1) == sigmoid(10x)
__device__ __forceinline__ float step_fast(float x) {
    return rcp_fast(1.0f + exp2_fast(x * (-10.0f * LOG2E)));
}
__device__ __forceinline__ float sinh_fast(float x) {
    float e = exp2_fast(x * LOG2E);
    return 0.5f * e - 0.5f * rcp_fast(e);
}

__device__ __forceinline__ float readlane_f(float x, int l) {
    return __builtin_bit_cast(float,
        __builtin_amdgcn_readlane(__builtin_bit_cast(int, x), l));
}

#define DPP_ADD(x, ctrl, rmask)                                                         \
    x += __builtin_bit_cast(float, __builtin_amdgcn_update_dpp(                         \
             0, __builtin_bit_cast(int, x), ctrl, rmask, 0xf, true))

// Full 64-lane sum via DPP; total lands in lane 63 -> readlane -> uniform.
__device__ __forceinline__ float wave_sum64(float x) {
    DPP_ADD(x, 0x111, 0xf);   // row_shr:1
    DPP_ADD(x, 0x112, 0xf);   // row_shr:2
    DPP_ADD(x, 0x114, 0xf);   // row_shr:4
    DPP_ADD(x, 0x118, 0xf);   // row_shr:8
    DPP_ADD(x, 0x142, 0xa);   // row_bcast:15
    DPP_ADD(x, 0x143, 0xc);   // row_bcast:31
    return readlane_f(x, 63);
}

// Barrier that waits ONLY on LDS ops (lgkmcnt), not global stores (vmcnt).
__device__ __forceinline__ void barrier_lgkm() {
    asm volatile("s_waitcnt lgkmcnt(0)" ::: "memory");
    __builtin_amdgcn_s_barrier();
    asm volatile("" ::: "memory");
}

#define CHUNK 1024

// ---------------------------------------------------------------------------
// RK4 scan: 128 threads = 2 waves (R11).
// R10 (4 waves) measured ~1040 busy + ~450 sync-stall cy/rhs. 2-wave K-split
// trades +200 cy issue (192 vs 96 layer-2 instrs) for cheaper sync: 2-wave
// barrier rendezvous, fan-in = ONE remote partial (own partial stays in
// registers), and the 3 step_fast transcendentals hoisted into the
// write->barrier window to hide under the rendezvous.
//   wave w owns K-rows [64w, 64w+64):
//     layer1: col 64w+lane (1 col/lane, no duplication)
//     layer2: 64 readlane + 128 fma (8 accs), cols lane & lane+64
//     fan-in: part[par][w][col]; read only other wave's slot
//     layer3/epilogue: replicated per wave (R10-proven wave_sum64 path)
// ---------------------------------------------------------------------------
extern "C" __global__ void
__attribute__((amdgpu_flat_work_group_size(128, 128), amdgpu_waves_per_eu(1, 1)))
scan_kernel(const float* __restrict__ x,
            const float* __restrict__ precp,
            const float* __restrict__ temp,
            const float* __restrict__ lday,
            const float* __restrict__ W1, const float* __restrict__ b1,
            const float* __restrict__ W2, const float* __restrict__ b2,
            const float* __restrict__ W3, const float* __restrict__ b3,
            float* __restrict__ sol, int T)
{
    const int tid  = threadIdx.x;      // 0..127
    const int lane = tid & 63;
    const int w    = tid >> 6;         // wave 0/1 (owns K-rows 64w..64w+63)
    const int kcol = (w << 6) + lane;  // layer-1 column this lane computes

    __shared__ float part[2][2][128];                  // [parity][wave][col]
    __shared__ float pr_s[CHUNK + 1], tm_s[CHUNK + 1], ld_s[CHUNK + 1];

    // ---- layer-1 weights for column kcol ----
    float w1q[4];
#pragma unroll
    for (int i = 0; i < 4; ++i) w1q[i] = W1[i * 128 + kcol];
    float b1q = b1[kcol];

    // ---- layer-2 weights: rows [64w,64w+64) of columns lane and lane+64 ----
    float w2a[64], w2b[64];
#pragma unroll
    for (int k = 0; k < 64; ++k) {
        const int row = (w << 6) + k;
        w2a[k] = W2[row * 128 + lane];
        w2b[k] = W2[row * 128 + lane + 64];
    }
    float b2a = b2[lane], b2b = b2[lane + 64];

    // ---- layer-3 weights: columns lane and lane+64 ----
    float w3a[5], w3b[5];
#pragma unroll
    for (int c = 0; c < 5; ++c) {
        w3a[c] = W3[lane * 5 + c];
        w3b[c] = W3[(lane + 64) * 5 + c];
    }
    const float b30 = b3[0], b31 = b3[1], b32 = b3[2], b33 = b3[3], b34 = b3[4];

    float S0 = x[0], S1 = x[1];
    if (tid == 0) { sol[0] = S0; sol[1] = S1; }

    auto rhs = [&](int par, float z0, float z1, float pr, float tm, float ld,
                   float& d0, float& d1) {
        // layer 1: one column per lane
        float a = b1q;
        a = fmaf(z0, w1q[0], a);
        a = fmaf(z1, w1q[1], a);
        a = fmaf(pr, w1q[2], a);
        a = fmaf(tm, w1q[3], a);
        const float h = tanh_fast(a);

        // layer 2: own 64 K-rows via readlane broadcast; 8 accumulators
        float aa0 = 0.f, aa1 = 0.f, aa2 = 0.f, aa3 = 0.f;
        float ab0 = 0.f, ab1 = 0.f, ab2 = 0.f, ab3 = 0.f;
#pragma unroll
        for (int k = 0; k < 64; k += 4) {
            const float hk0 = readlane_f(h, k);
            const float hk1 = readlane_f(h, k + 1);
            const float hk2 = readlane_f(h, k + 2);
            const float hk3 = readlane_f(h, k + 3);
            aa0 = fmaf(hk0, w2a[k],     aa0);
            ab0 = fmaf(hk0, w2b[k],     ab0);
            aa1 = fmaf(hk1, w2a[k + 1], aa1);
            ab1 = fmaf(hk1, w2b[k + 1], ab1);
            aa2 = fmaf(hk2, w2a[k + 2], aa2);
            ab2 = fmaf(hk2, w2b[k + 2], ab2);
            aa3 = fmaf(hk3, w2a[k + 3], aa3);
            ab3 = fmaf(hk3, w2b[k + 3], ab3);
        }
        const float own_a = (aa0 + aa1) + (aa2 + aa3);
        const float own_b = (ab0 + ab1) + (ab2 + ab3);
        part[par][w][lane]      = own_a;
        part[par][w][lane + 64] = own_b;

        // independent transcendentals INSIDE the write->barrier window:
        // they hide under the other wave's arrival skew.
        const float sS0 = step_fast(z0);
        const float sS1 = step_fast(z1);
        const float sNT = step_fast(-tm);

        barrier_lgkm();                                    // the ONE barrier

        // fan-in: only the OTHER wave's partial comes from LDS
        const float sa = own_a + part[par][w ^ 1][lane]      + b2a;
        const float sb = own_b + part[par][w ^ 1][lane + 64] + b2b;
        const float h2a = tanh_fast(sa);
        const float h2b = tanh_fast(sb);

        // layer 3: per-lane partials over 2 columns -> 5 wave sums (uniform)
        const float o0 = wave_sum64(fmaf(h2b, w3b[0], h2a * w3a[0])) + b30;
        const float o1 = wave_sum64(fmaf(h2b, w3b[1], h2a * w3a[1])) + b31;
        const float o2 = wave_sum64(fmaf(h2b, w3b[2], h2a * w3a[2])) + b32;
        const float o3 = wave_sum64(fmaf(h2b, w3b[3], h2a * w3a[3])) + b33;
        const float o4 = wave_sum64(fmaf(h2b, w3b[4], h2a * w3a[4])) + b34;

        // epilogue (uniform)
        const float melt = sS0 * sinh_fast(o2);            // relu(step)=step
        d0 = fmaxf(sinh_fast(o3) * sNT, 0.0f) - melt;
        d1 = fmaxf(sinh_fast(o4), 0.0f) + melt
             - sS1 * fmaf(ld, exp_fast(o0), exp_fast(o1));
    };

    // rolling register prefetch (B of step n == A of step n+1)
    float pB = precp[0], tB = temp[0], lB = lday[0];

    for (int cbase = 0; cbase < T - 1; cbase += CHUNK) {
        for (int i = tid; i <= CHUNK; i += 128) {
            int g = cbase + i;
            if (g < T) {
                pr_s[i] = precp[g];
                tm_s[i] = temp[g];
                ld_s[i] = lday[g];
            }
        }
        __syncthreads();

        const int len = min(T - 1 - cbase, CHUNK);
#pragma unroll 1
        for (int l = 0; l < len; ++l) {
            const float pA = pB, tA = tB, lA = lB;
            pB = pr_s[l + 1];
            tB = tm_s[l + 1];
            lB = ld_s[l + 1];
            const float pM = 0.5f * (pA + pB);
            const float tM = 0.5f * (tA + tB);
            const float lM = 0.5f * (lA + lB);

            float k10, k11, k20, k21, k30, k31, k40, k41;
            rhs(0, S0, S1, pA, tA, lA, k10, k11);                              // h = 1
            rhs(1, fmaf(0.5f, k10, S0), fmaf(0.5f, k11, S1), pM, tM, lM, k20, k21);
            rhs(0, fmaf(0.5f, k20, S0), fmaf(0.5f, k21, S1), pM, tM, lM, k30, k31);
            rhs(1, k30 + S0,            k31 + S1,            pB, tB, lB, k40, k41);

            const float c = 1.0f / 6.0f;
            S0 = S0 + c * (k10 + 2.0f * (k20 + k30) + k40);
            S1 = S1 + c * (k11 + 2.0f * (k21 + k31) + k41);
            if (tid == 0) {
                const int n = cbase + l;
                sol[2 * (n + 1)]     = S0;
                sol[2 * (n + 1) + 1] = S1;
            }
        }
        __syncthreads();   // protect series LDS re-stage vs stragglers
    }
}

// ---------------------------------------------------------------------------
// Output: y[t] = exp(mlp([sol0,sol1,x2,x3])[1]) — fully parallel, tiny.
// ---------------------------------------------------------------------------
extern "C" __global__ void __launch_bounds__(128)
out_kernel(const float* __restrict__ x,
           const float* __restrict__ sol,
           const float* __restrict__ W1, const float* __restrict__ b1,
           const float* __restrict__ W2, const float* __restrict__ b2,
           const float* __restrict__ W3, const float* __restrict__ b3,
           float* __restrict__ y, int T)
{
    const int j    = threadIdx.x;
    const int lane = j & 63;
    const int wv   = j >> 6;

    __shared__ __align__(16) float h1s[128];
    __shared__ float red[2];

    float w1c[4], w2c[128];
#pragma unroll
    for (int i = 0; i < 4; ++i)   w1c[i] = W1[i * 128 + j];
    const float b1j = b1[j];
#pragma unroll
    for (int i = 0; i < 128; ++i) w2c[i] = W2[i * 128 + j];
    const float b2j = b2[j];
    const float w31 = W3[j * 5 + 1];
    const float b31 = b3[1];

#pragma unroll 1
    for (int r = blockIdx.x; r < T; r += gridDim.x) {
        const float z0 = sol[2 * r], z1 = sol[2 * r + 1];
        const float z2 = x[4 * r + 2], z3 = x[4 * r + 3];
        float a = b1j;
        a = fmaf(z0, w1c[0], a);
        a = fmaf(z1, w1c[1], a);
        a = fmaf(z2, w1c[2], a);
        a = fmaf(z3, w1c[3], a);
        h1s[j] = tanh_fast(a);
        __syncthreads();
        float acc0 = 0.f, acc1 = 0.f, acc2 = 0.f, acc3 = 0.f;
#pragma unroll
        for (int i = 0; i < 128; i += 4) {
            const float4 hv = *reinterpret_cast<const float4*>(&h1s[i]);
            acc0 = fmaf(hv.x, w2c[i + 0], acc0);
            acc1 = fmaf(hv.y, w2c[i + 1], acc1);
            acc2 = fmaf(hv.z, w2c[i + 2], acc2);
            acc3 = fmaf(hv.w, w2c[i + 3], acc3);
        }
        const float h2 = tanh_fast(((acc0 + acc1) + (acc2 + acc3)) + b2j);
        float p = h2 * w31;
#pragma unroll
        for (int off = 32; off >= 1; off >>= 1)
            p += __shfl_xor(p, off);
        if (lane == 0) red[wv] = p;
        __syncthreads();
        if (j == 0) y[r] = exp_fast(red[0] + red[1] + b31);
        __syncthreads();
    }
}

// ---------------------------------------------------------------------------
extern "C" void kernel_launch(void* const* d_in, const int* in_sizes, int n_in,
                              void* d_out, int out_size, void* d_ws, size_t ws_size,
                              hipStream_t stream)
{
    const float* x      = (const float*)d_in[0];
    // d_in[1] = t_eval = arange(T) -> h == 1.0
    // d_in[2] = t_grid = arange(T)
    const float* precp  = (const float*)d_in[3];
    const float* temp   = (const float*)d_in[4];
    const float* lday   = (const float*)d_in[5];
    const float* W1     = (const float*)d_in[6];
    const float* b1     = (const float*)d_in[7];
    const float* W2     = (const float*)d_in[8];
    const float* b2     = (const float*)d_in[9];
    const float* W3     = (const float*)d_in[10];
    const float* b3     = (const float*)d_in[11];
    float*       y      = (float*)d_out;
    float*       sol    = (float*)d_ws;      // T*2 floats
    const int    T      = in_sizes[1];

    hipLaunchKernelGGL(scan_kernel, dim3(1), dim3(128), 0, stream,
                       x, precp, temp, lday,
                       W1, b1, W2, b2, W3, b3, sol, T);
    hipLaunchKernelGGL(out_kernel, dim3(256), dim3(128), 0, stream,
                       x, sol, W1, b1, W2, b2, W3, b3, y, T);
}